// Round 4
// baseline (136.838 us; speedup 1.0000x reference)
//
#include <hip/hip_runtime.h>

#define L 2048
#define BS 4
#define CIN 32
#define COUT 32
#define HIDN 64
#define KK 8
#define TB 8
#define EPSV 1e-5f
#define QSTR (HIDN*CIN + 8)   // 2056 f16 row stride: +16B pad -> a-frag reads at 4-cyc floor

typedef _Float16 f16;
typedef _Float16 f16x2 __attribute__((ext_vector_type(2)));
typedef _Float16 f16x8 __attribute__((ext_vector_type(8)));
typedef __fp16   h16x2 __attribute__((ext_vector_type(2)));   // cvt_pkrtz native type
typedef float    f32x2 __attribute__((ext_vector_type(2)));
typedef float    f32x4 __attribute__((ext_vector_type(4)));

// blocks 0..127: pack W2 into MFMA B-fragment order (f16); block 0 also zeroes LN sums.
// block 128: pack W1 into per-column f16 pairs: w1p[j*32 + i2*2 + {0,1}] = W1[{2i2,2i2+1}][j].
__global__ __launch_bounds__(64) void prep(const float* __restrict__ W2,
                                           const float* __restrict__ W1,
                                           f16* __restrict__ w2h,
                                           f16* __restrict__ w1p,
                                           float* __restrict__ sums) {
    const int f    = blockIdx.x;
    const int lane = threadIdx.x;
    if (f == 128) {
        #pragma unroll
        for (int i2 = 0; i2 < 16; i2++) {
            w1p[lane*32 + i2*2 + 0] = (f16)W1[(2*i2 + 0)*HIDN + lane];
            w1p[lane*32 + i2*2 + 1] = (f16)W1[(2*i2 + 1)*HIDN + lane];
        }
        return;
    }
    if (f == 0) sums[lane] = 0.f;
    const int kb = f >> 1, nt = f & 1;
    const int m = lane & 15, qd = lane >> 4;
    #pragma unroll
    for (int j = 0; j < 8; j++)
        w2h[(f*64 + lane)*8 + j] = (f16)W2[(kb*32 + qd*8 + j)*32 + nt*16 + m];
}

__global__ __launch_bounds__(256, 3) void cc_main(
    const float* __restrict__ times,
    const float* __restrict__ features,
    const int*   __restrict__ mask,
    const float* __restrict__ b1,
    const float* __restrict__ b2,
    const float* __restrict__ Wsk,
    const float* __restrict__ bsk,
    const f16*   __restrict__ w2h,
    const f16*   __restrict__ w1p,
    float* __restrict__ out,
    float* __restrict__ sums)
{
    __shared__ f16 s_Q[TB][QSTR];                    // ~32.9 KB
    __shared__ __align__(16) char pool[12288];       // 12 KB, phase-aliased
    f16   (*s_te)[KK][CIN]  = (f16  (*)[KK][CIN]) pool;             // A: 4 KB
    float (*s_f )[KK][CIN]  = (float(*)[KK][CIN])(pool + 4096);     // A: 8 KB
    float (*s_part)[TB][COUT] = (float(*)[TB][COUT]) pool;          // B: 4 KB (alias te)
    float (*s_r1)[COUT]     = (float(*)[COUT])(pool + 4096);        // B: 1 KB (alias f)
    float (*s_r2)[COUT]     = (float(*)[COUT])(pool + 5120);        // B: 1 KB
    __shared__ float s_F [TB][CIN];                  // 1 KB (not aliased)
    __shared__ float s_ft[TB][CIN];                  // 1 KB

    const int tid = threadIdx.x;
    const int tl  = tid >> 5;
    const int x   = tid & 31;
    const int bt  = blockIdx.x * TB + tl;
    const int b   = bt >> 11;
    const int t   = bt & (L - 1);

    // ---- Stage 1: te/f for all 8 k, native sin/cos (r <= 0.7 rad) ----
    const float t_cur = times[b*L + t];
    const int   np_t  = mask[b*L + t];
    // invpos = 10000^(-2*(x>>1)/32) = exp2(-(x>>1) * log2(10000)/16)
    const float inv_pos = exp2f(-(float)(x >> 1) * (13.2877123795f / 16.0f));
    float Fx = 0.f;
    for (int k = 0; k < KK; k++) {
        const int idx   = t - (KK - 1) + k;
        const int valid = idx >= 0;
        const int idxc  = valid ? idx : 0;
        const int dm    = valid && np_t && mask[b*L + idxc];
        const float dt  = dm ? (t_cur - times[b*L + idxc]) : 0.f;
        const float r   = dt * inv_pos;
        s_te[tl][k][x]  = (f16)((x & 1) ? __cosf(r) : __sinf(r));
        const float fv  = dm ? features[(b*L + idxc)*CIN + x] : 0.f;
        s_f[tl][k][x]   = fv;
        Fx += fv;
    }
    s_F [tl][x] = Fx;
    s_ft[tl][x] = features[(b*L + t)*CIN + x];

    // W1 columns x and x+32 as f16 pairs, register-resident
    union UH { f16x8 v8[4]; f16x2 v2[16]; };
    UH wa, wb;
    #pragma unroll
    for (int i = 0; i < 4; i++) {
        wa.v8[i] = ((const f16x8*)(w1p + x*32))[i];
        wb.v8[i] = ((const f16x8*)(w1p + (x + 32)*32))[i];
    }
    const float b1a = b1[x], b1b = b1[x + 32];
    __syncthreads();                                  // barrier 1

    // ---- Phase A: barrier-free k-loop, dot2 + pk_fma ----
    f32x2 q0[16], q1[16];
    #pragma unroll
    for (int c = 0; c < 16; c++) { q0[c] = (f32x2){0.f,0.f}; q1[c] = (f32x2){0.f,0.f}; }

    for (int k = 0; k < KK; k++) {
        union UT { f16x8 v8[4]; f16x2 v2[16]; } te;
        union UF { f32x4 v4[8]; f32x2 v2[16]; } ff;
        #pragma unroll
        for (int i = 0; i < 4; i++) te.v8[i] = ((const f16x8*)&s_te[tl][k][0])[i];
        #pragma unroll
        for (int i = 0; i < 8; i++) ff.v4[i] = ((const f32x4*)&s_f[tl][k][0])[i];

        float ha = b1a, hb = b1b;
        #pragma unroll
        for (int i2 = 0; i2 < 16; i2++) {
            ha = __builtin_amdgcn_fdot2(te.v2[i2], wa.v2[i2], ha, false);
            hb = __builtin_amdgcn_fdot2(te.v2[i2], wb.v2[i2], hb, false);
        }
        ha = fmaxf(ha, 0.f); hb = fmaxf(hb, 0.f);
        const f32x2 h2a = {ha, ha}, h2b = {hb, hb};
        #pragma unroll
        for (int c = 0; c < 16; c++) {
            q0[c] = h2a * ff.v2[c] + q0[c];           // v_pk_fma_f32
            q1[c] = h2b * ff.v2[c] + q1[c];
        }
    }

    // ---- Pack Q to f16 LDS (rows t-local, col hc = h*32+c) ----
    #pragma unroll
    for (int cj = 0; cj < 4; cj++) {
        const int cc = (x + cj) & 3;                  // rotation: fewer write conflicts
        union { f16x8 v8; h16x2 v2[4]; } p0, p1;
        #pragma unroll
        for (int j = 0; j < 4; j++) {
            p0.v2[j] = __builtin_amdgcn_cvt_pkrtz(q0[cc*4 + j][0], q0[cc*4 + j][1]);
            p1.v2[j] = __builtin_amdgcn_cvt_pkrtz(q1[cc*4 + j][0], q1[cc*4 + j][1]);
        }
        *(f16x8*)&s_Q[tl][x*32 + cc*8]          = p0.v8;
        *(f16x8*)&s_Q[tl][(x + 32)*32 + cc*8]   = p1.v8;
    }
    __syncthreads();                                  // barrier 2

    // extras (overlaps MFMA): b_skip + feat@Wsk + F@b2rows
    float ex = bsk[x];
    #pragma unroll
    for (int c = 0; c < CIN; c++) ex = fmaf(s_ft[tl][c], Wsk[c*COUT + x], ex);
    #pragma unroll
    for (int c = 0; c < CIN; c++) ex = fmaf(s_F [tl][c], b2 [c*COUT + x], ex);

    // ---- Phase B: MFMA, K=2048 split over 4 waves ----
    {
        const int wv   = tid >> 6;
        const int lane = tid & 63;
        const int m    = lane & 15, qd = lane >> 4;
        f32x4 C0 = {0.f,0.f,0.f,0.f}, C1 = {0.f,0.f,0.f,0.f};
        #pragma unroll 4
        for (int kb = wv*16; kb < wv*16 + 16; kb++) {
            const f16x8 a  = *(const f16x8*)&s_Q[m & 7][kb*32 + qd*8];
            const f16x8 bf0 = ((const f16x8*)w2h)[(kb*2 + 0)*64 + lane];
            const f16x8 bf1 = ((const f16x8*)w2h)[(kb*2 + 1)*64 + lane];
            C0 = __builtin_amdgcn_mfma_f32_16x16x32_f16(a, bf0, C0, 0, 0, 0);
            C1 = __builtin_amdgcn_mfma_f32_16x16x32_f16(a, bf1, C1, 0, 0, 0);
        }
        if (qd < 2) {
            #pragma unroll
            for (int r = 0; r < 4; r++) {
                s_part[wv][qd*4 + r][m]      = C0[r];
                s_part[wv][qd*4 + r][16 + m] = C1[r];
            }
        }
    }
    __syncthreads();                                  // barrier 3

    float val = ex;
    #pragma unroll
    for (int w = 0; w < 4; w++) val += s_part[w][tl][x];
    out[(b*L + t)*COUT + x] = val;
    s_r1[tl][x] = val;
    s_r2[tl][x] = val * val;
    __syncthreads();                                  // barrier 4
    if (tid < 32) {
        float s1 = 0.f, s2 = 0.f;
        #pragma unroll
        for (int j = 0; j < TB; j++) { s1 += s_r1[j][x]; s2 += s_r2[j][x]; }
        atomicAdd(&sums[x],      s1);
        atomicAdd(&sums[32 + x], s2);
    }
}

__global__ __launch_bounds__(256) void cc_norm(
    float4* __restrict__ out, const float* __restrict__ sums,
    const float* __restrict__ gamma, const float* __restrict__ beta)
{
    const int i  = blockIdx.x * 256 + threadIdx.x;    // float4 index
    const int o0 = (i & 7) * 4;
    const float n = (float)(BS * L);
    float4 v = out[i], r;
    float* vp = &v.x; float* rp = &r.x;
    #pragma unroll
    for (int j = 0; j < 4; j++) {
        const int o = o0 + j;
        const float mean = sums[o] / n;
        const float var  = sums[32 + o] / n - mean * mean;
        rp[j] = gamma[o] * (vp[j] - mean) * rsqrtf(var + EPSV) + beta[o];
    }
    out[i] = r;
}

extern "C" void kernel_launch(void* const* d_in, const int* in_sizes, int n_in,
                              void* d_out, int out_size, void* d_ws, size_t ws_size,
                              hipStream_t stream) {
    const float* times    = (const float*)d_in[0];
    const float* features = (const float*)d_in[1];
    const int*   mask     = (const int*)  d_in[2];
    const float* W1       = (const float*)d_in[3];
    const float* b1       = (const float*)d_in[4];
    const float* W2       = (const float*)d_in[5];
    const float* b2       = (const float*)d_in[6];
    const float* Wsk      = (const float*)d_in[7];
    const float* bsk      = (const float*)d_in[8];
    const float* gamma    = (const float*)d_in[9];
    const float* beta     = (const float*)d_in[10];
    float* out  = (float*)d_out;
    float* sums = (float*)d_ws;                          // 64 floats
    f16*   w2h  = (f16*)((char*)d_ws + 256);             // 128 KB
    f16*   w1p  = (f16*)((char*)d_ws + 256 + 131072);    // 4 KB

    prep<<<129, 64, 0, stream>>>(W2, W1, w2h, w1p, sums);
    cc_main<<<(BS*L)/TB, 256, 0, stream>>>(times, features, mask, b1,
                                           b2, Wsk, bsk, w2h, w1p, out, sums);
    cc_norm<<<(BS*L*COUT)/(4*256), 256, 0, stream>>>((float4*)out, sums, gamma, beta);
}